// Round 18
// baseline (97.919 us; speedup 1.0000x reference)
//
#include <hip/hip_runtime.h>
#include <hip/hip_bf16.h>

typedef __bf16 bf16;
typedef __bf16 bf16x8 __attribute__((ext_vector_type(8)));
typedef float f32x4 __attribute__((ext_vector_type(4)));

#define EMB 768
#define NH 12
#define HD 64
#define SEQ 2048
#define NBATCH 2
#define NREL (2 * SEQ - 1)
#define LOG2E 1.44269504088896f

// XOR-swizzle for 128B-row-stride LDS tiles (bits 9:7 -> 6:4). Involution.
__device__ __forceinline__ int swz(int bo) { return bo ^ ((bo >> 3) & 0x70); }
// XOR-swizzle for 256B-row-stride LDS tiles (bits 10:8 -> 6:4). Involution.
__device__ __forceinline__ int swz256(int bo) { return bo ^ ((bo >> 4) & 0x70); }
// K-row permutation making PV A-fragments lane-local (verified r2-r17).
__device__ __forceinline__ int kpos(int s) {
  return (s & 0x23) | ((s & 0x04) << 2) | ((s & 0x18) >> 1);
}
// raw v_exp_f32 (2^x); inputs <= 0 normals, denormal results flush to 0.
__device__ __forceinline__ float fexp2(float x) {
  return __builtin_amdgcn_exp2f(x);
}

// global -> LDS async 16B copy (wave-uniform LDS base, lane i at +i*16).
typedef __attribute__((address_space(3))) unsigned int lds_u32;
typedef __attribute__((address_space(1))) unsigned int glb_u32;
__device__ __forceinline__ void gld16(const void* g, void* l) {
  __builtin_amdgcn_global_load_lds((const glb_u32*)g, (lds_u32*)l, 16, 0, 0);
}

// ---------------- fused setup: cvt_x | cvt_w | bias table | mask bits -------
__global__ __launch_bounds__(256) void k_setup(
    const float* __restrict__ Xq, const float* __restrict__ Xk,
    const float* __restrict__ Xv, const float* __restrict__ Wq,
    const float* __restrict__ Wk, const float* __restrict__ Wv,
    const float* __restrict__ Wo, const unsigned char* __restrict__ mask,
    const float* __restrict__ rel_bias, bf16* __restrict__ ximg,
    bf16* __restrict__ wimg, float* __restrict__ bias_tab,
    unsigned long long* __restrict__ mbits) {
  __shared__ __align__(16) bf16 T[64 * 128];   // cvt_w scratch (swz256)
  const int idx = blockIdx.x;
  const int tid = threadIdx.x;
  if (idx < 1152) {               // ---- cvt_x: f32 -> bf16 swizzled images
    const int z = idx / 384, rem = idx % 384;
    const int mb = rem % 32, ks = rem / 32;
    const float* X = z == 0 ? Xq : z == 1 ? Xk : Xv;
    const int m0 = mb * 128, k0 = ks * 64;
    char* img = (char*)ximg + ((size_t)(z * 32 + mb) * 12 + ks) * 16384;
#pragma unroll
    for (int it = 0; it < 4; ++it) {
      int i = tid + it * 256;
      int mr = i >> 3, kc8 = (i & 7) * 8;
      const float* xp = X + (size_t)(m0 + mr) * EMB + k0 + kc8;
      float4 f0 = *(const float4*)xp, f1 = *(const float4*)(xp + 4);
      bf16x8 hh;
      hh[0] = (bf16)f0.x; hh[1] = (bf16)f0.y; hh[2] = (bf16)f0.z; hh[3] = (bf16)f0.w;
      hh[4] = (bf16)f1.x; hh[5] = (bf16)f1.y; hh[6] = (bf16)f1.z; hh[7] = (bf16)f1.w;
      *(bf16x8*)(img + swz(mr * 128 + kc8 * 2)) = hh;
    }
  } else if (idx < 1440) {        // ---- cvt_w: W[k][n] -> [n][k] images
    const int i = idx - 1152;
    const int z = i / 72, rem = i % 72;
    const int nb = rem % 6, ks = rem / 6;
    const float* W = z == 0 ? Wq : z == 1 ? Wk : z == 2 ? Wv : Wo;
    const int n0 = nb * 128, k0 = ks * 64;
    {
      int kk = tid >> 2, nn0 = (tid & 3) * 32;
      const float* wp = W + (size_t)(k0 + kk) * EMB + n0 + nn0;
#pragma unroll
      for (int jq = 0; jq < 4; ++jq) {
        float4 f0 = *(const float4*)(wp + jq * 8);
        float4 f1 = *(const float4*)(wp + jq * 8 + 4);
        bf16x8 hh;
        hh[0] = (bf16)f0.x; hh[1] = (bf16)f0.y; hh[2] = (bf16)f0.z; hh[3] = (bf16)f0.w;
        hh[4] = (bf16)f1.x; hh[5] = (bf16)f1.y; hh[6] = (bf16)f1.z; hh[7] = (bf16)f1.w;
        *(bf16x8*)((char*)T + swz256(kk * 256 + (nn0 + jq * 8) * 2)) = hh;
      }
    }
    __syncthreads();
    {
      int nr = tid >> 1, kh = tid & 1;
      char* img = (char*)wimg + ((size_t)(z * 6 + nb) * 12 + ks) * 16384;
#pragma unroll
      for (int jq = 0; jq < 4; ++jq) {
        union { bf16 e[8]; uint4 u; } pk;
#pragma unroll
        for (int q = 0; q < 8; ++q)
          pk.e[q] = *(const bf16*)((char*)T + swz256((kh * 32 + jq * 8 + q) * 256 + nr * 2));
        *(uint4*)(img + swz(nr * 128 + (kh * 32 + jq * 8) * 2)) = pk.u;
      }
    }
  } else if (idx < 1456) {        // ---- bias table (pre-scaled by log2e)
    int i = (idx - 1440) * 256 + tid;
    if (i < NREL) {
      int rel = i - (SEQ - 1);
      int bkt = (rel > 0) ? 16 : 0;
      int rp = rel < 0 ? -rel : rel;
      if (rp < 8) {
        bkt += rp;
      } else {
        float lf = (logf((float)rp * 0.125f) / 2.7725887222397811f) * 8.0f;
        int large = 8 + (int)lf;
        bkt += (large < 15) ? large : 15;
      }
      for (int h = 0; h < NH; ++h)
        bias_tab[h * NREL + i] = rel_bias[bkt * NH + h] * LOG2E;
    }
  } else {                        // ---- mask bits
    int wid = (idx - 1456) * 4 + (tid >> 6);
    int lane = tid & 63;
    int b = wid >> 5, wd = wid & 31;
    unsigned long long m = __ballot(mask[b * SEQ + wd * 64 + lane] != 0);
    if (lane == 0) mbits[wid] = m;
  }
}

// ---- QKV projection GEMM: pure-gld16 dbuf pipeline over tile images --------
// z=0: Q scaled (0.125*log2e) -> row-major. z=1: K -> K-tile images gk.
// z=2: V -> V^T images gv (direct, transposed).
__global__ __launch_bounds__(256) void k_proj_qkv(
    const bf16* __restrict__ ximg, const bf16* __restrict__ wimg,
    const float* __restrict__ bq, const float* __restrict__ bk,
    const float* __restrict__ bv, bf16* __restrict__ oq,
    bf16* __restrict__ gk, bf16* __restrict__ gv) {
  __shared__ __align__(16) bf16 AB[2][2][8192];  // [buf][A/B][16KB tile]
  const int z = blockIdx.z;
  const float* bias = z == 0 ? bq : z == 1 ? bk : bv;
  const float scale = z == 0 ? 0.125f * LOG2E : 1.0f;
  const int mb = blockIdx.x, nb = blockIdx.y;
  const int m0 = mb * 128, n0 = nb * 128;
  const int tid = threadIdx.x, lane = tid & 63, w = tid >> 6;
  const int c = lane & 15, g = lane >> 4;
  const int mo = (w >> 1) * 64, no = (w & 1) * 64;
  const char* abase = (const char*)ximg + (size_t)(z * 32 + mb) * 12 * 16384;
  const char* bbase = (const char*)wimg + (size_t)(z * 6 + nb) * 12 * 16384;

#define PISSUE(KS, BUF) do {                                               \
    const char* a_ = abase + (size_t)(KS) * 16384;                         \
    const char* b_ = bbase + (size_t)(KS) * 16384;                         \
    _Pragma("unroll") for (int ch = 0; ch < 4; ++ch) {                     \
      int ck = w * 4 + ch;                                                 \
      gld16(a_ + ck * 1024 + lane * 16, (char*)AB[BUF][0] + ck * 1024);    \
      gld16(b_ + ck * 1024 + lane * 16, (char*)AB[BUF][1] + ck * 1024);    \
    }                                                                      \
  } while (0)

  PISSUE(0, 0);
  f32x4 acc[4][4] = {};
  asm volatile("s_waitcnt vmcnt(0)" ::: "memory");
  __syncthreads();
  for (int ks = 0; ks < 12; ++ks) {
    const int cur = ks & 1;
    if (ks < 11) PISSUE(ks + 1, cur ^ 1);
    const char* As = (const char*)AB[cur][0];
    const char* Bs = (const char*)AB[cur][1];
    __builtin_amdgcn_s_setprio(1);
#pragma unroll
    for (int kk = 0; kk < 2; ++kk) {
      bf16x8 av[4], bvf[4];
#pragma unroll
      for (int mf = 0; mf < 4; ++mf)
        av[mf] = *(const bf16x8*)(As + swz((mo + mf * 16 + c) * 128 + kk * 64 + g * 16));
#pragma unroll
      for (int nf = 0; nf < 4; ++nf)
        bvf[nf] = *(const bf16x8*)(Bs + swz((no + nf * 16 + c) * 128 + kk * 64 + g * 16));
#pragma unroll
      for (int mf = 0; mf < 4; ++mf)
#pragma unroll
        for (int nf = 0; nf < 4; ++nf)
          acc[mf][nf] = __builtin_amdgcn_mfma_f32_16x16x32_bf16(bvf[nf], av[mf], acc[mf][nf], 0, 0, 0);
    }
    __builtin_amdgcn_s_setprio(0);
    if (ks < 11) {
      asm volatile("s_waitcnt vmcnt(0)" ::: "memory");
      __syncthreads();
    }
  }
  // epilogue: acc[mf][nf][r] = C[mo+mf*16+c][no+nf*16+g*4+r]
#pragma unroll
  for (int nf = 0; nf < 4; ++nf) {
    int n = n0 + no + nf * 16 + g * 4;
    float4 b4 = *(const float4*)&bias[n];
#pragma unroll
    for (int mf = 0; mf < 4; ++mf) {
      int m = m0 + mo + mf * 16 + c;
      float v0 = (acc[mf][nf][0] + b4.x) * scale;
      float v1 = (acc[mf][nf][1] + b4.y) * scale;
      float v2 = (acc[mf][nf][2] + b4.z) * scale;
      float v3 = (acc[mf][nf][3] + b4.w) * scale;
      if (z == 0) {
        union { bf16 e[4]; uint2 u; } pk;
        pk.e[0] = (bf16)v0; pk.e[1] = (bf16)v1; pk.e[2] = (bf16)v2; pk.e[3] = (bf16)v3;
        *(uint2*)(oq + (size_t)m * EMB + n) = pk.u;
      } else if (z == 1) {   // K image: byte swz(kpos(s)*128 + d*2) = K[s][d]
        int t = m >> 1, bb = m & 1;
        int hh = n >> 6, d = n & 63;
        union { bf16 e[4]; uint2 u; } pk;
        pk.e[0] = (bf16)v0; pk.e[1] = (bf16)v1; pk.e[2] = (bf16)v2; pk.e[3] = (bf16)v3;
        char* base = (char*)gk + ((size_t)(bb * NH + hh) * 32 + (t >> 6)) * 8192;
        *(uint2*)(base + swz(kpos(t & 63) * 128 + (d & ~7) * 2) + (d & 4) * 2) = pk.u;
      } else {               // V image: byte swz(d*128 + sc*2) = V[s0+sc][d]
        int s = m >> 1, bb = m & 1;
        int hh = n >> 6, d0 = n & 63;
        char* base = (char*)gv + ((size_t)(bb * NH + hh) * 32 + (s >> 6)) * 8192;
        int sc2 = (s & 63) * 2;
        *(bf16*)(base + (((d0 + 0) * 128 + sc2) ^ (((d0 + 0) & 7) << 4))) = (bf16)v0;
        *(bf16*)(base + (((d0 + 1) * 128 + sc2) ^ (((d0 + 1) & 7) << 4))) = (bf16)v1;
        *(bf16*)(base + (((d0 + 2) * 128 + sc2) ^ (((d0 + 2) & 7) << 4))) = (bf16)v2;
        *(bf16*)(base + (((d0 + 3) * 128 + sc2) ^ (((d0 + 3) & 7) << 4))) = (bf16)v3;
      }
    }
  }
#undef PISSUE
}

// ---- output projection: A-images (from merge) @ Wto images + bo -> f32 -----
__global__ __launch_bounds__(256) void k_proj_out(
    const bf16* __restrict__ aimg, const bf16* __restrict__ wimg,
    const float* __restrict__ bias, float* __restrict__ out) {
  __shared__ __align__(16) bf16 AB[2][2][8192];
  const int mb = blockIdx.x, nb = blockIdx.y;
  const int m0 = mb * 128, n0 = nb * 128;
  const int tid = threadIdx.x, lane = tid & 63, w = tid >> 6;
  const int c = lane & 15, g = lane >> 4;
  const int mo = (w >> 1) * 64, no = (w & 1) * 64;
  const char* abase = (const char*)aimg + (size_t)mb * 12 * 16384;
  const char* bbase = (const char*)wimg + (size_t)(3 * 6 + nb) * 12 * 16384;

#define PISSUE(KS, BUF) do {                                               \
    const char* a_ = abase + (size_t)(KS) * 16384;                         \
    const char* b_ = bbase + (size_t)(KS) * 16384;                         \
    _Pragma("unroll") for (int ch = 0; ch < 4; ++ch) {                     \
      int ck = w * 4 + ch;                                                 \
      gld16(a_ + ck * 1024 + lane * 16, (char*)AB[BUF][0] + ck * 1024);    \
      gld16(b_ + ck * 1024 + lane * 16, (char*)AB[BUF][1] + ck * 1024);    \
    }                                                                      \
  } while (0)

  PISSUE(0, 0);
  f32x4 acc[4][4] = {};
  asm volatile("s_waitcnt vmcnt(0)" ::: "memory");
  __syncthreads();
  for (int ks = 0; ks < 12; ++ks) {
    const int cur = ks & 1;
    if (ks < 11) PISSUE(ks + 1, cur ^ 1);
    const char* As = (const char*)AB[cur][0];
    const char* Bs = (const char*)AB[cur][1];
    __builtin_amdgcn_s_setprio(1);
#pragma unroll
    for (int kk = 0; kk < 2; ++kk) {
      bf16x8 av[4], bvf[4];
#pragma unroll
      for (int mf = 0; mf < 4; ++mf)
        av[mf] = *(const bf16x8*)(As + swz((mo + mf * 16 + c) * 128 + kk * 64 + g * 16));
#pragma unroll
      for (int nf = 0; nf < 4; ++nf)
        bvf[nf] = *(const bf16x8*)(Bs + swz((no + nf * 16 + c) * 128 + kk * 64 + g * 16));
#pragma unroll
      for (int mf = 0; mf < 4; ++mf)
#pragma unroll
        for (int nf = 0; nf < 4; ++nf)
          acc[mf][nf] = __builtin_amdgcn_mfma_f32_16x16x32_bf16(bvf[nf], av[mf], acc[mf][nf], 0, 0, 0);
    }
    __builtin_amdgcn_s_setprio(0);
    if (ks < 11) {
      asm volatile("s_waitcnt vmcnt(0)" ::: "memory");
      __syncthreads();
    }
  }
#pragma unroll
  for (int nf = 0; nf < 4; ++nf) {
    int n = n0 + no + nf * 16 + g * 4;
    float4 b4 = *(const float4*)&bias[n];
#pragma unroll
    for (int mf = 0; mf < 4; ++mf) {
      int m = m0 + mo + mf * 16 + c;
      float4 v;
      v.x = acc[mf][nf][0] + b4.x;
      v.y = acc[mf][nf][1] + b4.y;
      v.z = acc[mf][nf][2] + b4.z;
      v.w = acc[mf][nf][3] + b4.w;
      *(float4*)(out + (size_t)m * EMB + n) = v;
    }
  }
#undef PISSUE
}

// ----------------------------- flash attention ------------------------------
// r17 proven inner loop, s-split across blockIdx.z (flash-decoding style):
// block z handles s-tiles [z*16, z*16+16) with its OWN online softmax and
// writes unnormalized partials (o, m, l) to workspace. 1536 blocks -> 4
// blocks/CU (16 waves/CU). k_merge combines the halves.
__global__ __launch_bounds__(256, 4) void k_attn(
    const bf16* __restrict__ qb, const bf16* __restrict__ gk,
    const bf16* __restrict__ gv, const unsigned long long* __restrict__ mbits,
    const float* __restrict__ bias_tab, float* __restrict__ obuf,
    float* __restrict__ mlbuf) {
  __shared__ __align__(16) bf16 KV[2][2][4096];  // [buf][K/V][8KB image]
  __shared__ float Bslow[384];                   // bias (log2e) |rel|<192
  const int bh = blockIdx.x;
  const int b = bh / NH, h = bh % NH;
  const int t0 = blockIdx.y * 64;
  const int sh = blockIdx.z;                   // s-half: tiles [sh*16, sh*16+16)
  const int tid = threadIdx.x;
  const int lane = tid & 63, w = tid >> 6;
  const int c = lane & 15, g = lane >> 4;
  const float NEGINF = -__builtin_inff();
  const int tl = w * 16 + c;                   // this lane's t (block-local)

  const char* kimg = (const char*)gk + (size_t)bh * 32 * 8192;
  const char* vimg = (const char*)gv + (size_t)bh * 32 * 8192;

#define ISSUE(IT, BUF) do {                                                  \
    const char* ks_ = kimg + (size_t)(IT) * 8192;                            \
    const char* vs_ = vimg + (size_t)(IT) * 8192;                            \
    _Pragma("unroll") for (int jj = 0; jj < 2; ++jj) {                       \
      int ch = w * 2 + jj;                                                   \
      gld16(ks_ + ch * 1024 + lane * 16, (char*)KV[BUF][0] + ch * 1024);     \
      gld16(vs_ + ch * 1024 + lane * 16, (char*)KV[BUF][1] + ch * 1024);     \
    }                                                                        \
  } while (0)

  ISSUE(sh * 16, 0);
  // Q fragments (B operand), loop-invariant
  bf16x8 qf[2];
  {
    const bf16* qp = qb + (size_t)((t0 + tl) * NBATCH + b) * EMB + h * 64 + g * 8;
    qf[0] = *(const bf16x8*)qp;
    qf[1] = *(const bf16x8*)(qp + 32);
  }
  const float* btab = bias_tab + h * NREL + (SEQ - 1);
  for (int j = tid; j < 384; j += 256) Bslow[j] = btab[j - 192];
  const float cpos = btab[SEQ - 1];            // rel >= 128 (log2e units)
  const float cneg = btab[-(SEQ - 1)];         // rel <= -128

  bf16x8 ones8;                                // B-operand for l-sum MFMA
#pragma unroll
  for (int j = 0; j < 8; ++j) ones8[j] = (bf16)1.0f;

  float m_p = -1e30f;
  f32x4 lacc = {0.f, 0.f, 0.f, 0.f};           // row sums, O-row layout
  f32x4 o[4] = {};

  asm volatile("s_waitcnt vmcnt(0)" ::: "memory");
  __syncthreads();

#pragma unroll 2
  for (int it = 0; it < 16; ++it) {
    const int ita = sh * 16 + it;
    const int cur = it & 1;
    if (it < 15) ISSUE(ita + 1, cur ^ 1);
    const unsigned long long mb = mbits[b * 32 + ita];
    const char* Ks = (const char*)KV[cur][0];
    const char* Vs = (const char*)KV[cur][1];

    // QK^T (swapped): sacc[nf][r] = S'[t0+tl][s0 + 32*(nf>>1)+g*8+(nf&1)*4+r]
    f32x4 sacc[4] = {};
    __builtin_amdgcn_s_setprio(1);
#pragma unroll
    for (int kk = 0; kk < 2; ++kk) {
#pragma unroll
      for (int nf = 0; nf < 4; ++nf) {
        bf16x8 kf = *(const bf16x8*)(Ks + swz((nf * 16 + c) * 128 + kk * 64 + g * 16));
        sacc[nf] = __builtin_amdgcn_mfma_f32_16x16x32_bf16(kf, qf[kk], sacc[nf], 0, 0, 0);
      }
    }
    __builtin_amdgcn_s_setprio(0);

    const int s0 = ita * 64;
    const int d = s0 - t0;
    const bool slow = (d > -192) && (d < 192);
    const float cb = slow ? 0.f : (d >= 192 ? cpos : cneg);

    if (slow) {
      const int bidx = d - tl + 192;
#pragma unroll
      for (int nf = 0; nf < 4; ++nf) {
        int sb = 32 * (nf >> 1) + g * 8 + (nf & 1) * 4;
#pragma unroll
        for (int r = 0; r < 4; ++r) sacc[nf][r] += Bslow[bidx + sb + r];
      }
    }
    if (mb) {
#pragma unroll
      for (int nf = 0; nf < 4; ++nf) {
        int sb = 32 * (nf >> 1) + g * 8 + (nf & 1) * 4;
#pragma unroll
        for (int r = 0; r < 4; ++r)
          if ((mb >> (sb + r)) & 1) sacc[nf][r] = NEGINF;
      }
    }
    // per-lane partial max (tree, no shfl)
    f32x4 mx;
#pragma unroll
    for (int r = 0; r < 4; ++r)
      mx[r] = fmaxf(fmaxf(sacc[0][r], sacc[1][r]), fmaxf(sacc[2][r], sacc[3][r]));
    float pmax = fmaxf(fmaxf(mx[0], mx[1]), fmaxf(mx[2], mx[3]));

    // defer-max fast path: if ALL lanes' partial maxes are under threshold,
    // every row max is too -> skip the cross-lane reduce AND the rescale.
    if (!__all(pmax + cb <= m_p + 11.5f)) {
      float rmax = fmaxf(pmax, __shfl_xor(pmax, 16, 64));
      rmax = fmaxf(rmax, __shfl_xor(rmax, 32, 64));
      float rm = rmax + cb;                    // row max in score space
      float m_new = fmaxf(m_p, rm);
      float scl = fexp2(m_p - m_new);
      m_p = m_new;
#pragma unroll
      for (int r = 0; r < 4; ++r) {
        float so = __shfl(scl, g * 4 + r, 64);
        lacc[r] *= so;
#pragma unroll
        for (int nf2 = 0; nf2 < 4; ++nf2) o[nf2][r] *= so;
      }
    }
    const float msh = m_p - cb;
    bf16x8 pa[2];
#pragma unroll
    for (int kk = 0; kk < 2; ++kk)
#pragma unroll
      for (int j = 0; j < 8; ++j)
        pa[kk][j] = (bf16)fexp2(sacc[2 * kk + (j >> 2)][j & 3] - msh);

    // PV + l-sum (ones-B MFMA: lacc[r] accumulates row sums, O-row layout)
    __builtin_amdgcn_s_setprio(1);
    lacc = __builtin_amdgcn_mfma_f32_16x16x32_bf16(pa[0], ones8, lacc, 0, 0, 0);
    lacc = __builtin_amdgcn_mfma_f32_16x16x32_bf16(pa[1], ones8, lacc, 0, 0, 0);
#pragma unroll
    for (int kk = 0; kk < 2; ++kk) {
#pragma unroll
      for (int nf2 = 0; nf2 < 4; ++nf2) {
        bf16x8 vbf = *(const bf16x8*)(Vs + swz((nf2 * 16 + c) * 128 + kk * 64 + g * 16));
        o[nf2] = __builtin_amdgcn_mfma_f32_16x16x32_bf16(pa[kk], vbf, o[nf2], 0, 0, 0);
      }
    }
    __builtin_amdgcn_s_setprio(0);

    if (it < 15) {
      asm volatile("s_waitcnt vmcnt(0)" ::: "memory");
      __syncthreads();
    }
  }
  // epilogue: write unnormalized partials.
  // m per row tl=w*16+c (uniform over g); l per row w*16+g*4+r (uniform over c).
  const size_t pidx = ((size_t)(bh * 32 + blockIdx.y) * 2 + sh);
  float* ob = obuf + pidx * 4096;
  float* ml = mlbuf + pidx * 128;
  if (g == 0) ml[w * 16 + c] = m_p;
  if (c == 0) {
#pragma unroll
    for (int r = 0; r < 4; ++r) ml[64 + w * 16 + g * 4 + r] = lacc[r];
  }
#pragma unroll
  for (int r = 0; r < 4; ++r) {
    int trow = w * 16 + g * 4 + r;
#pragma unroll
    for (int nf2 = 0; nf2 < 4; ++nf2)
      ob[trow * 64 + nf2 * 16 + c] = o[nf2][r];
  }
#undef ISSUE
}

// ---- merge: combine s-half partials -> normalized bf16 A-images ------------
__global__ __launch_bounds__(256) void k_merge(
    const float* __restrict__ obuf, const float* __restrict__ mlbuf,
    bf16* __restrict__ aimg) {
  const int blk = blockIdx.x;           // bh*32 + tb
  const int bh = blk >> 5, tb = blk & 31;
  const int b = bh / NH, h = bh % NH;
  const int tid = threadIdx.x;
  const int tr = tid >> 2, dq = (tid & 3) * 16;
  const size_t p0 = (size_t)blk * 2 * 4096, p1 = p0 + 4096;
  const float* ml0 = mlbuf + (size_t)blk * 2 * 128;
  const float* ml1 = ml0 + 128;
  float m0 = ml0[tr], l0 = ml0[64 + tr];
  float m1 = ml1[tr], l1 = ml1[64 + tr];
  float M = fmaxf(m0, m1);
  float a0 = fexp2(m0 - M), a1 = fexp2(m1 - M);
  float inv = 1.0f / (l0 * a0 + l1 * a1);
  a0 *= inv; a1 *= inv;
  int t = tb * 64 + tr;
  int m = t * NBATCH + b;
  char* base = (char*)aimg + ((size_t)(m >> 7) * 12 + h) * 16384;
  int mr128 = (m & 127) * 128;
  union { bf16 e[16]; uint4 u[2]; } pk;
#pragma unroll
  for (int j = 0; j < 16; ++j) {
    float v = obuf[p0 + tr * 64 + dq + j] * a0 + obuf[p1 + tr * 64 + dq + j] * a1;
    pk.e[j] = (bf16)v;
  }
  *(uint4*)(base + swz(mr128 + dq * 2)) = pk.u[0];
  *(uint4*)(base + swz(mr128 + (dq + 8) * 2)) = pk.u[1];
}

extern "C" void kernel_launch(void* const* d_in, const int* in_sizes, int n_in,
                              void* d_out, int out_size, void* d_ws, size_t ws_size,
                              hipStream_t stream) {
  const float* query = (const float*)d_in[0];
  const float* key_ = (const float*)d_in[1];
  const float* value = (const float*)d_in[2];
  const unsigned char* kpm = (const unsigned char*)d_in[3];
  const float* Wq = (const float*)d_in[4];
  const float* bq = (const float*)d_in[5];
  const float* Wk = (const float*)d_in[6];
  const float* bk = (const float*)d_in[7];
  const float* Wv = (const float*)d_in[8];
  const float* bv = (const float*)d_in[9];
  const float* Wo = (const float*)d_in[10];
  const float* bo = (const float*)d_in[11];
  const float* rel_bias = (const float*)d_in[12];
  float* out = (float*)d_out;

  char* ws = (char*)d_ws;
  const size_t SZb = (size_t)SEQ * NBATCH * EMB * sizeof(bf16);   // 6.29 MB
  const size_t WIMG = (size_t)4 * 6 * 12 * 16384;                 // 4.72 MB
  bf16* qbb = (bf16*)(ws);                                        // Q rows
  bf16* gkb = (bf16*)(ws + SZb);                                  // K images
  bf16* gvb = (bf16*)(ws + 2 * SZb);                              // V images
  bf16* wimg = (bf16*)(ws + 3 * SZb);                             // W images
  float* bias_tab = (float*)(ws + 3 * SZb + WIMG);                // 196 KB
  unsigned long long* mbits =
      (unsigned long long*)(ws + 3 * SZb + WIMG + 196608);        // 512 B
  bf16* ximg = (bf16*)(ws + 3 * SZb + WIMG + 196608 + 512);       // 18.9 MB
  bf16* aimg = ximg;  // X images dead after k_proj_qkv; reuse for attn output
  char* pws = ws + 3 * SZb + WIMG + 196608 + 512 + (size_t)3 * 32 * 12 * 16384;
  float* obuf = (float*)pws;                                      // 25.2 MB
  float* mlbuf = (float*)(pws + (size_t)768 * 2 * 4096 * 4);      // 786 KB

  k_setup<<<1472, 256, 0, stream>>>(query, key_, value, Wq, Wk, Wv, Wo,
                                    kpm, rel_bias, ximg, wimg, bias_tab, mbits);
  k_proj_qkv<<<dim3(32, 6, 3), 256, 0, stream>>>(
      ximg, wimg, bq, bk, bv, qbb, gkb, gvb);
  k_attn<<<dim3(NBATCH * NH, SEQ / 64, 2), 256, 0, stream>>>(
      qbb, gkb, gvb, mbits, bias_tab, obuf, mlbuf);
  k_merge<<<NBATCH * NH * 32, 256, 0, stream>>>(obuf, mlbuf, aimg);
  k_proj_out<<<dim3(32, 6), 256, 0, stream>>>(aimg, wimg, bo, out);
}

// Round 19
// 91.646 us; speedup vs baseline: 1.0684x; 1.0684x over previous
//
#include <hip/hip_runtime.h>
#include <hip/hip_bf16.h>

typedef __bf16 bf16;
typedef __bf16 bf16x8 __attribute__((ext_vector_type(8)));
typedef float f32x4 __attribute__((ext_vector_type(4)));

#define EMB 768
#define NH 12
#define HD 64
#define SEQ 2048
#define NBATCH 2
#define NREL (2 * SEQ - 1)
#define LOG2E 1.44269504088896f

// XOR-swizzle for 128B-row-stride LDS tiles (bits 9:7 -> 6:4). Involution.
__device__ __forceinline__ int swz(int bo) { return bo ^ ((bo >> 3) & 0x70); }
// XOR-swizzle for 256B-row-stride LDS tiles (bits 10:8 -> 6:4). Involution.
__device__ __forceinline__ int swz256(int bo) { return bo ^ ((bo >> 4) & 0x70); }
// K-row permutation making PV A-fragments lane-local (verified r2-r17).
__device__ __forceinline__ int kpos(int s) {
  return (s & 0x23) | ((s & 0x04) << 2) | ((s & 0x18) >> 1);
}
// raw v_exp_f32 (2^x); inputs <= 0 normals, denormal results flush to 0.
__device__ __forceinline__ float fexp2(float x) {
  return __builtin_amdgcn_exp2f(x);
}

// global -> LDS async 16B copy (wave-uniform LDS base, lane i at +i*16).
typedef __attribute__((address_space(3))) unsigned int lds_u32;
typedef __attribute__((address_space(1))) unsigned int glb_u32;
__device__ __forceinline__ void gld16(const void* g, void* l) {
  __builtin_amdgcn_global_load_lds((const glb_u32*)g, (lds_u32*)l, 16, 0, 0);
}

// ---------------- fused setup: cvt_x | cvt_w | bias table | mask bits -------
__global__ __launch_bounds__(256) void k_setup(
    const float* __restrict__ Xq, const float* __restrict__ Xk,
    const float* __restrict__ Xv, const float* __restrict__ Wq,
    const float* __restrict__ Wk, const float* __restrict__ Wv,
    const float* __restrict__ Wo, const unsigned char* __restrict__ mask,
    const float* __restrict__ rel_bias, bf16* __restrict__ ximg,
    bf16* __restrict__ wimg, float* __restrict__ bias_tab,
    unsigned long long* __restrict__ mbits) {
  __shared__ __align__(16) bf16 T[64 * 128];   // cvt_w scratch (swz256)
  const int idx = blockIdx.x;
  const int tid = threadIdx.x;
  if (idx < 1152) {               // ---- cvt_x: f32 -> bf16 swizzled images
    const int z = idx / 384, rem = idx % 384;
    const int mb = rem % 32, ks = rem / 32;
    const float* X = z == 0 ? Xq : z == 1 ? Xk : Xv;
    const int m0 = mb * 128, k0 = ks * 64;
    char* img = (char*)ximg + ((size_t)(z * 32 + mb) * 12 + ks) * 16384;
#pragma unroll
    for (int it = 0; it < 4; ++it) {
      int i = tid + it * 256;
      int mr = i >> 3, kc8 = (i & 7) * 8;
      const float* xp = X + (size_t)(m0 + mr) * EMB + k0 + kc8;
      float4 f0 = *(const float4*)xp, f1 = *(const float4*)(xp + 4);
      bf16x8 hh;
      hh[0] = (bf16)f0.x; hh[1] = (bf16)f0.y; hh[2] = (bf16)f0.z; hh[3] = (bf16)f0.w;
      hh[4] = (bf16)f1.x; hh[5] = (bf16)f1.y; hh[6] = (bf16)f1.z; hh[7] = (bf16)f1.w;
      *(bf16x8*)(img + swz(mr * 128 + kc8 * 2)) = hh;
    }
  } else if (idx < 1440) {        // ---- cvt_w: W[k][n] -> [n][k] images
    const int i = idx - 1152;
    const int z = i / 72, rem = i % 72;
    const int nb = rem % 6, ks = rem / 6;
    const float* W = z == 0 ? Wq : z == 1 ? Wk : z == 2 ? Wv : Wo;
    const int n0 = nb * 128, k0 = ks * 64;
    {
      int kk = tid >> 2, nn0 = (tid & 3) * 32;
      const float* wp = W + (size_t)(k0 + kk) * EMB + n0 + nn0;
#pragma unroll
      for (int jq = 0; jq < 4; ++jq) {
        float4 f0 = *(const float4*)(wp + jq * 8);
        float4 f1 = *(const float4*)(wp + jq * 8 + 4);
        bf16x8 hh;
        hh[0] = (bf16)f0.x; hh[1] = (bf16)f0.y; hh[2] = (bf16)f0.z; hh[3] = (bf16)f0.w;
        hh[4] = (bf16)f1.x; hh[5] = (bf16)f1.y; hh[6] = (bf16)f1.z; hh[7] = (bf16)f1.w;
        *(bf16x8*)((char*)T + swz256(kk * 256 + (nn0 + jq * 8) * 2)) = hh;
      }
    }
    __syncthreads();
    {
      int nr = tid >> 1, kh = tid & 1;
      char* img = (char*)wimg + ((size_t)(z * 6 + nb) * 12 + ks) * 16384;
#pragma unroll
      for (int jq = 0; jq < 4; ++jq) {
        union { bf16 e[8]; uint4 u; } pk;
#pragma unroll
        for (int q = 0; q < 8; ++q)
          pk.e[q] = *(const bf16*)((char*)T + swz256((kh * 32 + jq * 8 + q) * 256 + nr * 2));
        *(uint4*)(img + swz(nr * 128 + (kh * 32 + jq * 8) * 2)) = pk.u;
      }
    }
  } else if (idx < 1456) {        // ---- bias table (pre-scaled by log2e)
    int i = (idx - 1440) * 256 + tid;
    if (i < NREL) {
      int rel = i - (SEQ - 1);
      int bkt = (rel > 0) ? 16 : 0;
      int rp = rel < 0 ? -rel : rel;
      if (rp < 8) {
        bkt += rp;
      } else {
        float lf = (logf((float)rp * 0.125f) / 2.7725887222397811f) * 8.0f;
        int large = 8 + (int)lf;
        bkt += (large < 15) ? large : 15;
      }
      for (int h = 0; h < NH; ++h)
        bias_tab[h * NREL + i] = rel_bias[bkt * NH + h] * LOG2E;
    }
  } else {                        // ---- mask bits
    int wid = (idx - 1456) * 4 + (tid >> 6);
    int lane = tid & 63;
    int b = wid >> 5, wd = wid & 31;
    unsigned long long m = __ballot(mask[b * SEQ + wd * 64 + lane] != 0);
    if (lane == 0) mbits[wid] = m;
  }
}

// ---- QKV projection GEMM: pure-gld16 dbuf pipeline over tile images --------
// z=0: Q scaled (0.125*log2e) -> row-major. z=1: K -> K-tile images gk.
// z=2: V -> V^T images gv (direct, transposed).
__global__ __launch_bounds__(256) void k_proj_qkv(
    const bf16* __restrict__ ximg, const bf16* __restrict__ wimg,
    const float* __restrict__ bq, const float* __restrict__ bk,
    const float* __restrict__ bv, bf16* __restrict__ oq,
    bf16* __restrict__ gk, bf16* __restrict__ gv) {
  __shared__ __align__(16) bf16 AB[2][2][8192];  // [buf][A/B][16KB tile]
  const int z = blockIdx.z;
  const float* bias = z == 0 ? bq : z == 1 ? bk : bv;
  const float scale = z == 0 ? 0.125f * LOG2E : 1.0f;
  const int mb = blockIdx.x, nb = blockIdx.y;
  const int m0 = mb * 128, n0 = nb * 128;
  const int tid = threadIdx.x, lane = tid & 63, w = tid >> 6;
  const int c = lane & 15, g = lane >> 4;
  const int mo = (w >> 1) * 64, no = (w & 1) * 64;
  const char* abase = (const char*)ximg + (size_t)(z * 32 + mb) * 12 * 16384;
  const char* bbase = (const char*)wimg + (size_t)(z * 6 + nb) * 12 * 16384;

#define PISSUE(KS, BUF) do {                                               \
    const char* a_ = abase + (size_t)(KS) * 16384;                         \
    const char* b_ = bbase + (size_t)(KS) * 16384;                         \
    _Pragma("unroll") for (int ch = 0; ch < 4; ++ch) {                     \
      int ck = w * 4 + ch;                                                 \
      gld16(a_ + ck * 1024 + lane * 16, (char*)AB[BUF][0] + ck * 1024);    \
      gld16(b_ + ck * 1024 + lane * 16, (char*)AB[BUF][1] + ck * 1024);    \
    }                                                                      \
  } while (0)

  PISSUE(0, 0);
  f32x4 acc[4][4] = {};
  asm volatile("s_waitcnt vmcnt(0)" ::: "memory");
  __syncthreads();
  for (int ks = 0; ks < 12; ++ks) {
    const int cur = ks & 1;
    if (ks < 11) PISSUE(ks + 1, cur ^ 1);
    const char* As = (const char*)AB[cur][0];
    const char* Bs = (const char*)AB[cur][1];
    __builtin_amdgcn_s_setprio(1);
#pragma unroll
    for (int kk = 0; kk < 2; ++kk) {
      bf16x8 av[4], bvf[4];
#pragma unroll
      for (int mf = 0; mf < 4; ++mf)
        av[mf] = *(const bf16x8*)(As + swz((mo + mf * 16 + c) * 128 + kk * 64 + g * 16));
#pragma unroll
      for (int nf = 0; nf < 4; ++nf)
        bvf[nf] = *(const bf16x8*)(Bs + swz((no + nf * 16 + c) * 128 + kk * 64 + g * 16));
#pragma unroll
      for (int mf = 0; mf < 4; ++mf)
#pragma unroll
        for (int nf = 0; nf < 4; ++nf)
          acc[mf][nf] = __builtin_amdgcn_mfma_f32_16x16x32_bf16(bvf[nf], av[mf], acc[mf][nf], 0, 0, 0);
    }
    __builtin_amdgcn_s_setprio(0);
    if (ks < 11) {
      asm volatile("s_waitcnt vmcnt(0)" ::: "memory");
      __syncthreads();
    }
  }
  // epilogue: acc[mf][nf][r] = C[mo+mf*16+c][no+nf*16+g*4+r]
#pragma unroll
  for (int nf = 0; nf < 4; ++nf) {
    int n = n0 + no + nf * 16 + g * 4;
    float4 b4 = *(const float4*)&bias[n];
#pragma unroll
    for (int mf = 0; mf < 4; ++mf) {
      int m = m0 + mo + mf * 16 + c;
      float v0 = (acc[mf][nf][0] + b4.x) * scale;
      float v1 = (acc[mf][nf][1] + b4.y) * scale;
      float v2 = (acc[mf][nf][2] + b4.z) * scale;
      float v3 = (acc[mf][nf][3] + b4.w) * scale;
      if (z == 0) {
        union { bf16 e[4]; uint2 u; } pk;
        pk.e[0] = (bf16)v0; pk.e[1] = (bf16)v1; pk.e[2] = (bf16)v2; pk.e[3] = (bf16)v3;
        *(uint2*)(oq + (size_t)m * EMB + n) = pk.u;
      } else if (z == 1) {   // K image: byte swz(kpos(s)*128 + d*2) = K[s][d]
        int t = m >> 1, bb = m & 1;
        int hh = n >> 6, d = n & 63;
        union { bf16 e[4]; uint2 u; } pk;
        pk.e[0] = (bf16)v0; pk.e[1] = (bf16)v1; pk.e[2] = (bf16)v2; pk.e[3] = (bf16)v3;
        char* base = (char*)gk + ((size_t)(bb * NH + hh) * 32 + (t >> 6)) * 8192;
        *(uint2*)(base + swz(kpos(t & 63) * 128 + (d & ~7) * 2) + (d & 4) * 2) = pk.u;
      } else {               // V image: byte swz(d*128 + sc*2) = V[s0+sc][d]
        int s = m >> 1, bb = m & 1;
        int hh = n >> 6, d0 = n & 63;
        char* base = (char*)gv + ((size_t)(bb * NH + hh) * 32 + (s >> 6)) * 8192;
        int sc2 = (s & 63) * 2;
        *(bf16*)(base + (((d0 + 0) * 128 + sc2) ^ (((d0 + 0) & 7) << 4))) = (bf16)v0;
        *(bf16*)(base + (((d0 + 1) * 128 + sc2) ^ (((d0 + 1) & 7) << 4))) = (bf16)v1;
        *(bf16*)(base + (((d0 + 2) * 128 + sc2) ^ (((d0 + 2) & 7) << 4))) = (bf16)v2;
        *(bf16*)(base + (((d0 + 3) * 128 + sc2) ^ (((d0 + 3) & 7) << 4))) = (bf16)v3;
      }
    }
  }
#undef PISSUE
}

// ---- output projection: A-images (from attn) @ Wto images + bo -> f32 ------
__global__ __launch_bounds__(256) void k_proj_out(
    const bf16* __restrict__ aimg, const bf16* __restrict__ wimg,
    const float* __restrict__ bias, float* __restrict__ out) {
  __shared__ __align__(16) bf16 AB[2][2][8192];
  const int mb = blockIdx.x, nb = blockIdx.y;
  const int m0 = mb * 128, n0 = nb * 128;
  const int tid = threadIdx.x, lane = tid & 63, w = tid >> 6;
  const int c = lane & 15, g = lane >> 4;
  const int mo = (w >> 1) * 64, no = (w & 1) * 64;
  const char* abase = (const char*)aimg + (size_t)mb * 12 * 16384;
  const char* bbase = (const char*)wimg + (size_t)(3 * 6 + nb) * 12 * 16384;

#define PISSUE(KS, BUF) do {                                               \
    const char* a_ = abase + (size_t)(KS) * 16384;                         \
    const char* b_ = bbase + (size_t)(KS) * 16384;                         \
    _Pragma("unroll") for (int ch = 0; ch < 4; ++ch) {                     \
      int ck = w * 4 + ch;                                                 \
      gld16(a_ + ck * 1024 + lane * 16, (char*)AB[BUF][0] + ck * 1024);    \
      gld16(b_ + ck * 1024 + lane * 16, (char*)AB[BUF][1] + ck * 1024);    \
    }                                                                      \
  } while (0)

  PISSUE(0, 0);
  f32x4 acc[4][4] = {};
  asm volatile("s_waitcnt vmcnt(0)" ::: "memory");
  __syncthreads();
  for (int ks = 0; ks < 12; ++ks) {
    const int cur = ks & 1;
    if (ks < 11) PISSUE(ks + 1, cur ^ 1);
    const char* As = (const char*)AB[cur][0];
    const char* Bs = (const char*)AB[cur][1];
    __builtin_amdgcn_s_setprio(1);
#pragma unroll
    for (int kk = 0; kk < 2; ++kk) {
      bf16x8 av[4], bvf[4];
#pragma unroll
      for (int mf = 0; mf < 4; ++mf)
        av[mf] = *(const bf16x8*)(As + swz((mo + mf * 16 + c) * 128 + kk * 64 + g * 16));
#pragma unroll
      for (int nf = 0; nf < 4; ++nf)
        bvf[nf] = *(const bf16x8*)(Bs + swz((no + nf * 16 + c) * 128 + kk * 64 + g * 16));
#pragma unroll
      for (int mf = 0; mf < 4; ++mf)
#pragma unroll
        for (int nf = 0; nf < 4; ++nf)
          acc[mf][nf] = __builtin_amdgcn_mfma_f32_16x16x32_bf16(bvf[nf], av[mf], acc[mf][nf], 0, 0, 0);
    }
    __builtin_amdgcn_s_setprio(0);
    if (ks < 11) {
      asm volatile("s_waitcnt vmcnt(0)" ::: "memory");
      __syncthreads();
    }
  }
#pragma unroll
  for (int nf = 0; nf < 4; ++nf) {
    int n = n0 + no + nf * 16 + g * 4;
    float4 b4 = *(const float4*)&bias[n];
#pragma unroll
    for (int mf = 0; mf < 4; ++mf) {
      int m = m0 + mo + mf * 16 + c;
      float4 v;
      v.x = acc[mf][nf][0] + b4.x;
      v.y = acc[mf][nf][1] + b4.y;
      v.z = acc[mf][nf][2] + b4.z;
      v.w = acc[mf][nf][3] + b4.w;
      *(float4*)(out + (size_t)m * EMB + n) = v;
    }
  }
#undef PISSUE
}

// ----------------------------- flash attention ------------------------------
// r12 proven structure + unroll-2 main loop + defer fast-path (verified r14:
// attn 48 us). Byte-identical to round 17's k_attn.
__global__ __launch_bounds__(256, 4) void k_attn(
    const bf16* __restrict__ qb, const bf16* __restrict__ gk,
    const bf16* __restrict__ gv, const unsigned long long* __restrict__ mbits,
    const float* __restrict__ bias_tab, bf16* __restrict__ aimg) {
  __shared__ __align__(16) bf16 KV[2][2][4096];  // [buf][K/V][8KB image]
  __shared__ float Bslow[384];                   // bias (log2e) |rel|<192
  const int bh = blockIdx.x;
  const int b = bh / NH, h = bh % NH;
  const int t0 = blockIdx.y * 64;
  const int tid = threadIdx.x;
  const int lane = tid & 63, w = tid >> 6;
  const int c = lane & 15, g = lane >> 4;
  const float NEGINF = -__builtin_inff();
  const int tl = w * 16 + c;                   // this lane's t (block-local)

  const char* kimg = (const char*)gk + (size_t)bh * 32 * 8192;
  const char* vimg = (const char*)gv + (size_t)bh * 32 * 8192;

#define ISSUE(IT, BUF) do {                                                  \
    const char* ks_ = kimg + (size_t)(IT) * 8192;                            \
    const char* vs_ = vimg + (size_t)(IT) * 8192;                            \
    _Pragma("unroll") for (int jj = 0; jj < 2; ++jj) {                       \
      int ch = w * 2 + jj;                                                   \
      gld16(ks_ + ch * 1024 + lane * 16, (char*)KV[BUF][0] + ch * 1024);     \
      gld16(vs_ + ch * 1024 + lane * 16, (char*)KV[BUF][1] + ch * 1024);     \
    }                                                                        \
  } while (0)

  ISSUE(0, 0);
  // Q fragments (B operand), loop-invariant
  bf16x8 qf[2];
  {
    const bf16* qp = qb + (size_t)((t0 + tl) * NBATCH + b) * EMB + h * 64 + g * 8;
    qf[0] = *(const bf16x8*)qp;
    qf[1] = *(const bf16x8*)(qp + 32);
  }
  const float* btab = bias_tab + h * NREL + (SEQ - 1);
  for (int j = tid; j < 384; j += 256) Bslow[j] = btab[j - 192];
  const float cpos = btab[SEQ - 1];            // rel >= 128 (log2e units)
  const float cneg = btab[-(SEQ - 1)];         // rel <= -128

  bf16x8 ones8;                                // B-operand for l-sum MFMA
#pragma unroll
  for (int j = 0; j < 8; ++j) ones8[j] = (bf16)1.0f;

  float m_p = -1e30f;
  f32x4 lacc = {0.f, 0.f, 0.f, 0.f};           // row sums, O-row layout
  f32x4 o[4] = {};

  asm volatile("s_waitcnt vmcnt(0)" ::: "memory");
  __syncthreads();

#pragma unroll 2
  for (int it = 0; it < 32; ++it) {
    const int cur = it & 1;
    if (it < 31) ISSUE(it + 1, cur ^ 1);
    const unsigned long long mb = mbits[b * 32 + it];
    const char* Ks = (const char*)KV[cur][0];
    const char* Vs = (const char*)KV[cur][1];

    // QK^T (swapped): sacc[nf][r] = S'[t0+tl][s0 + 32*(nf>>1)+g*8+(nf&1)*4+r]
    f32x4 sacc[4] = {};
    __builtin_amdgcn_s_setprio(1);
#pragma unroll
    for (int kk = 0; kk < 2; ++kk) {
#pragma unroll
      for (int nf = 0; nf < 4; ++nf) {
        bf16x8 kf = *(const bf16x8*)(Ks + swz((nf * 16 + c) * 128 + kk * 64 + g * 16));
        sacc[nf] = __builtin_amdgcn_mfma_f32_16x16x32_bf16(kf, qf[kk], sacc[nf], 0, 0, 0);
      }
    }
    __builtin_amdgcn_s_setprio(0);

    const int s0 = it * 64;
    const int d = s0 - t0;
    const bool slow = (d > -192) && (d < 192);
    const float cb = slow ? 0.f : (d >= 192 ? cpos : cneg);

    if (slow) {
      const int bidx = d - tl + 192;
#pragma unroll
      for (int nf = 0; nf < 4; ++nf) {
        int sb = 32 * (nf >> 1) + g * 8 + (nf & 1) * 4;
#pragma unroll
        for (int r = 0; r < 4; ++r) sacc[nf][r] += Bslow[bidx + sb + r];
      }
    }
    if (mb) {
#pragma unroll
      for (int nf = 0; nf < 4; ++nf) {
        int sb = 32 * (nf >> 1) + g * 8 + (nf & 1) * 4;
#pragma unroll
        for (int r = 0; r < 4; ++r)
          if ((mb >> (sb + r)) & 1) sacc[nf][r] = NEGINF;
      }
    }
    // per-lane partial max (tree, no shfl)
    f32x4 mx;
#pragma unroll
    for (int r = 0; r < 4; ++r)
      mx[r] = fmaxf(fmaxf(sacc[0][r], sacc[1][r]), fmaxf(sacc[2][r], sacc[3][r]));
    float pmax = fmaxf(fmaxf(mx[0], mx[1]), fmaxf(mx[2], mx[3]));

    // defer-max fast path: if ALL lanes' partial maxes are under threshold,
    // every row max is too -> skip the cross-lane reduce AND the rescale.
    if (!__all(pmax + cb <= m_p + 11.5f)) {
      float rmax = fmaxf(pmax, __shfl_xor(pmax, 16, 64));
      rmax = fmaxf(rmax, __shfl_xor(rmax, 32, 64));
      float rm = rmax + cb;                    // row max in score space
      float m_new = fmaxf(m_p, rm);
      float scl = fexp2(m_p - m_new);
      m_p = m_new;
#pragma unroll
      for (int r = 0; r < 4; ++r) {
        float so = __shfl(scl, g * 4 + r, 64);
        lacc[r] *= so;
#pragma unroll
        for (int nf2 = 0; nf2 < 4; ++nf2) o[nf2][r] *= so;
      }
    }
    const float msh = m_p - cb;
    bf16x8 pa[2];
#pragma unroll
    for (int kk = 0; kk < 2; ++kk)
#pragma unroll
      for (int j = 0; j < 8; ++j)
        pa[kk][j] = (bf16)fexp2(sacc[2 * kk + (j >> 2)][j & 3] - msh);

    // PV + l-sum (ones-B MFMA: lacc[r] accumulates row sums, O-row layout)
    __builtin_amdgcn_s_setprio(1);
    lacc = __builtin_amdgcn_mfma_f32_16x16x32_bf16(pa[0], ones8, lacc, 0, 0, 0);
    lacc = __builtin_amdgcn_mfma_f32_16x16x32_bf16(pa[1], ones8, lacc, 0, 0, 0);
#pragma unroll
    for (int kk = 0; kk < 2; ++kk) {
#pragma unroll
      for (int nf2 = 0; nf2 < 4; ++nf2) {
        bf16x8 vbf = *(const bf16x8*)(Vs + swz((nf2 * 16 + c) * 128 + kk * 64 + g * 16));
        o[nf2] = __builtin_amdgcn_mfma_f32_16x16x32_bf16(pa[kk], vbf, o[nf2], 0, 0, 0);
      }
    }
    __builtin_amdgcn_s_setprio(0);

    if (it < 31) {
      asm volatile("s_waitcnt vmcnt(0)" ::: "memory");
      __syncthreads();
    }
  }
  // epilogue: O rows t = t0 + w*16 + g*4 + r; l is per-lane (lacc[r])
#pragma unroll
  for (int r = 0; r < 4; ++r) {
    float inv = 1.0f / lacc[r];
    int t = t0 + w * 16 + g * 4 + r;
    int m = t * NBATCH + b;
    char* base = (char*)aimg + ((size_t)(m >> 7) * 12 + h) * 16384;
    int mr128 = (m & 127) * 128;
#pragma unroll
    for (int nf2 = 0; nf2 < 4; ++nf2) {
      int dd = nf2 * 16 + c;
      *(bf16*)(base + swz(mr128 + dd * 2)) = (bf16)(o[nf2][r] * inv);
    }
  }
#undef ISSUE
}

extern "C" void kernel_launch(void* const* d_in, const int* in_sizes, int n_in,
                              void* d_out, int out_size, void* d_ws, size_t ws_size,
                              hipStream_t stream) {
  const float* query = (const float*)d_in[0];
  const float* key_ = (const float*)d_in[1];
  const float* value = (const float*)d_in[2];
  const unsigned char* kpm = (const unsigned char*)d_in[3];
  const float* Wq = (const float*)d_in[4];
  const float* bq = (const float*)d_in[5];
  const float* Wk = (const float*)d_in[6];
  const float* bk = (const float*)d_in[7];
  const float* Wv = (const float*)d_in[8];
  const float* bv = (const float*)d_in[9];
  const float* Wo = (const float*)d_in[10];
  const float* bo = (const float*)d_in[11];
  const float* rel_bias = (const float*)d_in[12];
  float* out = (float*)d_out;

  char* ws = (char*)d_ws;
  const size_t SZb = (size_t)SEQ * NBATCH * EMB * sizeof(bf16);   // 6.29 MB
  const size_t WIMG = (size_t)4 * 6 * 12 * 16384;                 // 4.72 MB
  bf16* qbb = (bf16*)(ws);                                        // Q rows
  bf16* gkb = (bf16*)(ws + SZb);                                  // K images
  bf16* gvb = (bf16*)(ws + 2 * SZb);                              // V images
  bf16* wimg = (bf16*)(ws + 3 * SZb);                             // W images
  float* bias_tab = (float*)(ws + 3 * SZb + WIMG);                // 196 KB
  unsigned long long* mbits =
      (unsigned long long*)(ws + 3 * SZb + WIMG + 196608);        // 512 B
  bf16* ximg = (bf16*)(ws + 3 * SZb + WIMG + 196608 + 512);       // 18.9 MB
  bf16* aimg = ximg;  // X images dead after k_proj_qkv; reuse for attn output

  k_setup<<<1472, 256, 0, stream>>>(query, key_, value, Wq, Wk, Wv, Wo,
                                    kpm, rel_bias, ximg, wimg, bias_tab, mbits);
  k_proj_qkv<<<dim3(32, 6, 3), 256, 0, stream>>>(
      ximg, wimg, bq, bk, bv, qbb, gkb, gvb);
  k_attn<<<dim3(NBATCH * NH, SEQ / 64), 256, 0, stream>>>(
      qbb, gkb, gvb, mbits, bias_tab, aimg);
  k_proj_out<<<dim3(32, 6), 256, 0, stream>>>(aimg, wimg, bo, out);
}